// Round 11
// baseline (1238.127 us; speedup 1.0000x reference)
//
#include <hip/hip_runtime.h>
#include <hip/hip_bf16.h>

#define NN 100000
#define NE 1600000
#define D 128
#define NB2 1563   // fine buckets of 64 nodes (dst >> 6)
#define BSH2 6
#define CAP2 1280  // padded capacity (mean 1024, sigma ~32 -> 8 sigma)

static constexpr int NA    = (NE + 4095) / 4096;   // 391 edge chunks
static constexpr int NGEMM = (NN + 63) / 64;       // 1563 gemm tiles

// ---------------- workspace layout ----------------
static constexpr size_t SUP_OFF   = 0;
static constexpr size_t SUP_BYTES = (((size_t)NN * D * 2) + 15) & ~(size_t)15;   // 25.6 MB bf16
static constexpr size_t CUR_OFF   = SUP_OFF + SUP_BYTES;
static constexpr size_t CUR_BY    = (((size_t)NB2 * 4) + 15) & ~(size_t)15;
static constexpr size_t WT_OFF    = CUR_OFF + CUR_BY;
static constexpr size_t WT_BY     = (size_t)D * D * 2;                            // 32 KB bf16 W^T
static constexpr size_t STG_OFF   = WT_OFF + WT_BY;
static constexpr size_t STG_BY    = (size_t)NB2 * CAP2 * 8;                       // 16.0 MB

typedef __attribute__((ext_vector_type(8))) short short8v;   // 8 bf16 (4 VGPRs)
typedef __attribute__((ext_vector_type(4))) float float4v;   // MFMA C/D + nt f32x4

__device__ __forceinline__ unsigned pk_bf16(float a, float b) {
  __hip_bfloat16 x = __float2bfloat16(a), y = __float2bfloat16(b);
  return (unsigned)*(unsigned short*)&x | ((unsigned)*(unsigned short*)&y << 16);
}

// ---------------- K0: W -> bf16^T  +  zero bucket cursors ----------------
__global__ __launch_bounds__(256) void k0_prep(const float* __restrict__ W,
                                               unsigned short* __restrict__ Wt,
                                               int* __restrict__ cursor) {
  const int i = blockIdx.x * 256 + threadIdx.x;
  if (i < D * D) {
    const int k = i >> 7, c = i & 127;
    __hip_bfloat16 h = __float2bfloat16(W[i]);
    Wt[c * D + k] = *(unsigned short*)&h;
  }
  if (i < NB2) cursor[i] = 0;
}

// ---------------- kgemm: support = feat @ W via MFMA bf16 ----------------
__global__ __launch_bounds__(256) void kgemm(const float* __restrict__ feat,
                                             const unsigned short* __restrict__ Wt,
                                             unsigned short* __restrict__ sup) {
  __shared__ char Wl[32768];
  const int t = threadIdx.x;
  {
    const uint4* g = (const uint4*)Wt;
    for (int i = t; i < 2048; i += 256) {
      const int b = i << 4;
      *(uint4*)&Wl[b ^ (((b >> 8) & 7) << 4)] = g[i];
    }
  }
  __syncthreads();

  const int wv = t >> 6, l = t & 63;
  const int lm = l & 15, lk = l >> 4;
  const int r0 = blockIdx.x * 64 + wv * 16;
  int row = r0 + lm;
  if (row >= NN) row = NN - 1;  // clamp; stores are guarded
  const float* fr = feat + (size_t)row * D;

  short8v A[4];
#pragma unroll
  for (int ks = 0; ks < 4; ++ks) {
    const float4 u = *(const float4*)(fr + ks * 32 + lk * 8);
    const float4 v = *(const float4*)(fr + ks * 32 + lk * 8 + 4);
    union { unsigned w[4]; short8v s; } cv;
    cv.w[0] = pk_bf16(u.x, u.y);
    cv.w[1] = pk_bf16(u.z, u.w);
    cv.w[2] = pk_bf16(v.x, v.y);
    cv.w[3] = pk_bf16(v.z, v.w);
    A[ks] = cv.s;
  }

  float4v acc[8];
#pragma unroll
  for (int ct = 0; ct < 8; ++ct) acc[ct] = (float4v){0.f, 0.f, 0.f, 0.f};

#pragma unroll
  for (int ct = 0; ct < 8; ++ct) {
    const int c = ct * 16 + lm;
#pragma unroll
    for (int ks = 0; ks < 4; ++ks) {
      int b = c * 256 + ks * 64 + lk * 16;
      b ^= ((c & 7) << 4);
      const short8v Bf = *(const short8v*)&Wl[b];
      acc[ct] = __builtin_amdgcn_mfma_f32_16x16x32_bf16(A[ks], Bf, acc[ct], 0, 0, 0);
    }
  }

#pragma unroll
  for (int j = 0; j < 4; ++j) {
    const int rr = r0 + lk * 4 + j;
    if (rr < NN) {
      unsigned short* srow = sup + (size_t)rr * D + lm;
#pragma unroll
      for (int ct = 0; ct < 8; ++ct) {
        __hip_bfloat16 h = __float2bfloat16(acc[ct][j]);
        srow[ct * 16] = *(unsigned short*)&h;
      }
    }
  }
}

// ---------------- pass A: multisplit into PADDED fine buckets ----------------
// stg word: lo = src | (dst&63)<<17 ; hi = val fp32 bits; bucket b at stg + b*CAP2
__global__ __launch_bounds__(256) void kpassA(const int* __restrict__ src,
                                              const int* __restrict__ dst,
                                              const float* __restrict__ val,
                                              int* __restrict__ cursor,
                                              unsigned long long* __restrict__ stg) {
  __shared__ int h4[4 * NB2];   // 25 KB
  __shared__ int base[NB2];     // 6.25 KB
  const int t = threadIdx.x;
  for (int i = t; i < 4 * NB2; i += 256) h4[i] = 0;
  __syncthreads();
  const int e0 = blockIdx.x * 4096;
  const int hb = (t >> 6) * NB2;
  int d[16];
#pragma unroll
  for (int k = 0; k < 16; ++k) {
    const int e = e0 + t + k * 256;
    d[k] = (e < NE) ? dst[e] : -1;
    if (d[k] >= 0) atomicAdd(&h4[hb + (d[k] >> BSH2)], 1);
  }
  __syncthreads();
  for (int i = t; i < NB2; i += 256) {
    const int hs = h4[i] + h4[NB2 + i] + h4[2 * NB2 + i] + h4[3 * NB2 + i];
    base[i] = hs ? atomicAdd(&cursor[i], hs) : 0;
  }
  __syncthreads();
#pragma unroll
  for (int k = 0; k < 16; ++k) {
    const int e = e0 + t + k * 256;
    if (d[k] >= 0) {
      const int bk = d[k] >> BSH2;
      const int pos = atomicAdd(&base[bk], 1);
      if (pos < CAP2) {
        const unsigned lo = (unsigned)src[e] | ((unsigned)(d[k] & 63) << 17);
        const unsigned hi = __float_as_uint(val[e]);
        stg[(size_t)bk * CAP2 + pos] = (unsigned long long)lo | ((unsigned long long)hi << 32);
      }
    }
  }
}

// ---------------- gatherB: per-bucket LDS fp32 accumulate + epilogue ----------------
// One block per 64-node bucket. acc layout column-permuted: col 2l -> [l], col 2l+1 -> [64+l]
// so ds_add_f32 is 2-way bank (free). Edge record broadcast via v_readlane (no shfl DS cost).
__global__ __launch_bounds__(256) void kgatherB(const unsigned short* __restrict__ sup,
                                                const int* __restrict__ cursor,
                                                const unsigned long long* __restrict__ stg,
                                                const float* __restrict__ feat,
                                                const float* __restrict__ bias,
                                                float* __restrict__ out) {
  __shared__ float acc[64 * 128];  // 32 KB
  const int b = blockIdx.x;
  const int t = threadIdx.x;
  {
    float4v* a4 = (float4v*)acc;
#pragma unroll
    for (int i = t; i < 2048; i += 256) a4[i] = (float4v){0.f, 0.f, 0.f, 0.f};
  }
  __syncthreads();

  const int cnt0 = cursor[b];
  const int cnt = cnt0 > CAP2 ? CAP2 : cnt0;
  const size_t bb = (size_t)b * CAP2;
  const int l = t & 63, w = t >> 6;
  const unsigned* sup32 = (const unsigned*)sup;  // dword view: row*64 + l -> cols {2l, 2l+1}

  for (int base = w * 64; base < cnt; base += 256) {
    int batch = cnt - base;
    if (batch > 64) batch = 64;
    unsigned rlo = 0, rhi = 0;
    if (l < batch) {
      const unsigned long long rec = __builtin_nontemporal_load(stg + bb + base + l);
      rlo = (unsigned)rec;
      rhi = (unsigned)(rec >> 32);
    }
    if (batch == 64) {
#pragma unroll
      for (int sub = 0; sub < 8; ++sub) {
        unsigned lo[8];
        unsigned q[8];
#pragma unroll
        for (int j = 0; j < 8; ++j) {
          lo[j] = (unsigned)__builtin_amdgcn_readlane((int)rlo, sub * 8 + j);
          q[j] = sup32[(size_t)(lo[j] & 0x1FFFFu) * 64 + l];
        }
#pragma unroll
        for (int j = 0; j < 8; ++j) {
          const float vv = __uint_as_float((unsigned)__builtin_amdgcn_readlane((int)rhi, sub * 8 + j));
          const int dr = (lo[j] >> 17) & 63;
          atomicAdd(&acc[dr * 128 + l],      __uint_as_float(q[j] << 16) * vv);
          atomicAdd(&acc[dr * 128 + 64 + l], __uint_as_float(q[j] & 0xffff0000u) * vv);
        }
      }
    } else {
      for (int i = 0; i < batch; ++i) {
        const unsigned lo = (unsigned)__builtin_amdgcn_readlane((int)rlo, i);
        const float vv = __uint_as_float((unsigned)__builtin_amdgcn_readlane((int)rhi, i));
        const unsigned q = sup32[(size_t)(lo & 0x1FFFFu) * 64 + l];
        const int dr = (lo >> 17) & 63;
        atomicAdd(&acc[dr * 128 + l],      __uint_as_float(q << 16) * vv);
        atomicAdd(&acc[dr * 128 + 64 + l], __uint_as_float(q & 0xffff0000u) * vv);
      }
    }
  }
  __syncthreads();

  // epilogue: thread t handles node t>>2, cols [(t&3)*32, +32)
  const int nl = t >> 2;
  const int n = b * 64 + nl;
  if (n < NN) {
    const int c0 = (t & 3) * 32;
    const float* arow = &acc[nl * 128];
    const float* frt = feat + (size_t)n * D;
    float* orow = out + (size_t)n * D;
#pragma unroll
    for (int c = c0; c < c0 + 32; c += 4) {
      const float4v f = __builtin_nontemporal_load((const float4v*)(frt + c));
      const float4v bv = *(const float4v*)(bias + c);
      float4v o;
      o.x = fmaxf(arow[((c + 0) >> 1) + ((c + 0) & 1) * 64] + bv.x, 0.f) + f.x;
      o.y = fmaxf(arow[((c + 1) >> 1) + ((c + 1) & 1) * 64] + bv.y, 0.f) + f.y;
      o.z = fmaxf(arow[((c + 2) >> 1) + ((c + 2) & 1) * 64] + bv.z, 0.f) + f.z;
      o.w = fmaxf(arow[((c + 3) >> 1) + ((c + 3) & 1) * 64] + bv.w, 0.f) + f.w;
      __builtin_nontemporal_store(o, (float4v*)(orow + c));
    }
  }
}

extern "C" void kernel_launch(void* const* d_in, const int* in_sizes, int n_in,
                              void* d_out, int out_size, void* d_ws, size_t ws_size,
                              hipStream_t stream) {
  const float* feat = (const float*)d_in[0];
  const int*   esrc = (const int*)d_in[1];
  const int*   edst = (const int*)d_in[2];
  const float* eval = (const float*)d_in[3];
  const float* W    = (const float*)d_in[4];
  const float* bias = (const float*)d_in[5];
  float* out = (float*)d_out;
  char*  ws  = (char*)d_ws;

  unsigned short*     sup    = (unsigned short*)(ws + SUP_OFF);
  int*                cursor = (int*)(ws + CUR_OFF);
  unsigned short*     Wt     = (unsigned short*)(ws + WT_OFF);
  unsigned long long* stg    = (unsigned long long*)(ws + STG_OFF);

  // K0: W -> bf16^T + zero cursors
  k0_prep<<<64, 256, 0, stream>>>(W, Wt, cursor);
  // K1: MFMA GEMM
  kgemm<<<NGEMM, 256, 0, stream>>>(feat, Wt, sup);
  // K2: multisplit into padded fine buckets (no scan, no passB)
  kpassA<<<NA, 256, 0, stream>>>(esrc, edst, eval, cursor, stg);
  // K3: per-bucket LDS accumulate + bias + relu + residual
  kgatherB<<<NB2, 256, 0, stream>>>(sup, cursor, stg, feat, bias, out);
}

// Round 12
// 137.912 us; speedup vs baseline: 8.9777x; 8.9777x over previous
//
#include <hip/hip_runtime.h>
#include <hip/hip_bf16.h>

#define NN 100000
#define NE 1600000
#define D 128
#define NB 196   // buckets of 512 nodes (dst >> 9)
#define BSH 9
#define CAP 10240  // padded bucket capacity (mean 8192, sigma ~90 -> 22 sigma)

static constexpr int NA    = (NE + 4095) / 4096;   // 391 edge chunks
static constexpr int NGEMM = (NN + 63) / 64;       // 1563 gemm tiles

// ---------------- workspace layout ----------------
static constexpr size_t SUP_OFF    = 0;
static constexpr size_t SUP_BYTES  = (((size_t)NN * D * 2) + 15) & ~(size_t)15;   // 25.6 MB bf16
static constexpr size_t RB_OFF     = SUP_OFF + SUP_BYTES;
static constexpr size_t RB_BY      = (((size_t)NN * 4) + 15) & ~(size_t)15;
static constexpr size_t RE_OFF     = RB_OFF + RB_BY;
static constexpr size_t RE_BY      = (((size_t)NN * 4) + 15) & ~(size_t)15;
static constexpr size_t CUR_OFF    = RE_OFF + RE_BY;
static constexpr size_t CUR_BY     = (((size_t)NB * 4) + 15) & ~(size_t)15;
static constexpr size_t WT_OFF     = CUR_OFF + CUR_BY;
static constexpr size_t WT_BY      = (size_t)D * D * 2;                            // 32 KB bf16 W^T
static constexpr size_t STG_OFF    = WT_OFF + WT_BY;
static constexpr size_t STG_BY     = (size_t)NB * CAP * 8;                         // 16.1 MB
static constexpr size_t EDG_OFF    = STG_OFF + STG_BY;
static constexpr size_t EDG_BY     = (size_t)NB * CAP * 4;                         // 8.0 MB

typedef __attribute__((ext_vector_type(8))) short short8v;   // 8 bf16 (4 VGPRs)
typedef __attribute__((ext_vector_type(4))) float float4v;   // MFMA C/D + nt f32x4
typedef __attribute__((ext_vector_type(4))) unsigned uint4v; // nt u32x4

__device__ __forceinline__ unsigned pk_bf16(float a, float b) {
  __hip_bfloat16 x = __float2bfloat16(a), y = __float2bfloat16(b);
  return (unsigned)*(unsigned short*)&x | ((unsigned)*(unsigned short*)&y << 16);
}

// ---------------- K0: W -> bf16^T  +  zero bucket cursors ----------------
__global__ __launch_bounds__(256) void k0_prep(const float* __restrict__ W,
                                               unsigned short* __restrict__ Wt,
                                               int* __restrict__ cursor) {
  const int i = blockIdx.x * 256 + threadIdx.x;
  if (i < D * D) {
    const int k = i >> 7, c = i & 127;
    __hip_bfloat16 h = __float2bfloat16(W[i]);
    Wt[c * D + k] = *(unsigned short*)&h;
  }
  if (blockIdx.x == 0 && threadIdx.x < NB) cursor[threadIdx.x] = 0;
}

// ---------------- kgemm: support = feat @ W via MFMA bf16 ----------------
__global__ __launch_bounds__(256) void kgemm(const float* __restrict__ feat,
                                             const unsigned short* __restrict__ Wt,
                                             unsigned short* __restrict__ sup) {
  __shared__ char Wl[32768];
  const int t = threadIdx.x;
  {
    const uint4* g = (const uint4*)Wt;
    for (int i = t; i < 2048; i += 256) {
      const int b = i << 4;
      *(uint4*)&Wl[b ^ (((b >> 8) & 7) << 4)] = g[i];
    }
  }
  __syncthreads();

  const int wv = t >> 6, l = t & 63;
  const int lm = l & 15, lk = l >> 4;
  const int r0 = blockIdx.x * 64 + wv * 16;
  int row = r0 + lm;
  if (row >= NN) row = NN - 1;  // clamp; stores are guarded
  const float* fr = feat + (size_t)row * D;

  short8v A[4];
#pragma unroll
  for (int ks = 0; ks < 4; ++ks) {
    const float4 u = *(const float4*)(fr + ks * 32 + lk * 8);
    const float4 v = *(const float4*)(fr + ks * 32 + lk * 8 + 4);
    union { unsigned w[4]; short8v s; } cv;
    cv.w[0] = pk_bf16(u.x, u.y);
    cv.w[1] = pk_bf16(u.z, u.w);
    cv.w[2] = pk_bf16(v.x, v.y);
    cv.w[3] = pk_bf16(v.z, v.w);
    A[ks] = cv.s;
  }

  float4v acc[8];
#pragma unroll
  for (int ct = 0; ct < 8; ++ct) acc[ct] = (float4v){0.f, 0.f, 0.f, 0.f};

#pragma unroll
  for (int ct = 0; ct < 8; ++ct) {
    const int c = ct * 16 + lm;
#pragma unroll
    for (int ks = 0; ks < 4; ++ks) {
      int b = c * 256 + ks * 64 + lk * 16;
      b ^= ((c & 7) << 4);
      const short8v Bf = *(const short8v*)&Wl[b];
      acc[ct] = __builtin_amdgcn_mfma_f32_16x16x32_bf16(A[ks], Bf, acc[ct], 0, 0, 0);
    }
  }

#pragma unroll
  for (int j = 0; j < 4; ++j) {
    const int rr = r0 + lk * 4 + j;
    if (rr < NN) {
      unsigned short* srow = sup + (size_t)rr * D + lm;
#pragma unroll
      for (int ct = 0; ct < 8; ++ct) {
        __hip_bfloat16 h = __float2bfloat16(acc[ct][j]);
        srow[ct * 16] = *(unsigned short*)&h;
      }
    }
  }
}

// ---------------- pass A: multisplit into PADDED buckets (no pre-hist, no scan) ----------------
// stg word: lo = src | (dst&511)<<17 ; hi = val fp32 bits; bucket b at stg + b*CAP
__global__ __launch_bounds__(256) void kpassA(const int* __restrict__ src,
                                              const int* __restrict__ dst,
                                              const float* __restrict__ val,
                                              int* __restrict__ cursor,
                                              unsigned long long* __restrict__ stg) {
  __shared__ int h4[4 * NB];
  __shared__ int h[NB];
  __shared__ int base[NB];
  const int t = threadIdx.x;
  for (int i = t; i < 4 * NB; i += 256) h4[i] = 0;
  __syncthreads();
  const int e0 = blockIdx.x * 4096;
  const int hb = (t >> 6) * NB;
  int d[16];
#pragma unroll
  for (int k = 0; k < 16; ++k) {
    const int e = e0 + t + k * 256;
    d[k] = (e < NE) ? dst[e] : -1;
    if (d[k] >= 0) atomicAdd(&h4[hb + (d[k] >> BSH)], 1);
  }
  __syncthreads();
  for (int i = t; i < NB; i += 256)
    h[i] = h4[i] + h4[NB + i] + h4[2 * NB + i] + h4[3 * NB + i];
  __syncthreads();
  for (int i = t; i < NB; i += 256)
    base[i] = h[i] ? atomicAdd(&cursor[i], h[i]) : 0;
  __syncthreads();
#pragma unroll
  for (int k = 0; k < 16; ++k) {
    const int e = e0 + t + k * 256;
    if (d[k] >= 0) {
      const int bk = d[k] >> BSH;
      const int pos = atomicAdd(&base[bk], 1);
      const unsigned lo = (unsigned)src[e] | ((unsigned)(d[k] & 511) << 17);
      const unsigned hi = __float_as_uint(val[e]);
      stg[(size_t)bk * CAP + pos] = (unsigned long long)lo | ((unsigned long long)hi << 32);
    }
  }
}

// ---------------- pass B: per-bucket exact CSR in padded layout; 4B edge records ----------------
// record = src(17b) | bf16(val)<<17 ; per-node rowBeg/rowEnd (padded layout)
__global__ __launch_bounds__(256) void kpassB(const unsigned long long* __restrict__ stg,
                                              const int* __restrict__ cursor,
                                              int* __restrict__ rowBeg,
                                              int* __restrict__ rowEnd,
                                              unsigned* __restrict__ edges) {
  __shared__ int hist[512];
  __shared__ int start[512];
  __shared__ int psum[256];
  const int b = blockIdx.x;
  const int t = threadIdx.x;
  const int cnt = cursor[b];
  const int base = b * CAP;
  hist[t] = 0;
  hist[t + 256] = 0;
  __syncthreads();
  for (int i = t; i < cnt; i += 256)
    atomicAdd(&hist[((unsigned)stg[base + i] >> 17) & 511], 1);
  __syncthreads();
  const int h0 = hist[2 * t], h1 = hist[2 * t + 1];
  const int p = h0 + h1;
  psum[t] = p;
  __syncthreads();
#pragma unroll
  for (int off = 1; off < 256; off <<= 1) {
    const int x = (t >= off) ? psum[t - off] : 0;
    __syncthreads();
    psum[t] += x;
    __syncthreads();
  }
  const int ex = psum[t] - p;
  start[2 * t] = ex;
  start[2 * t + 1] = ex + h0;
  __syncthreads();
  const int node0 = b << BSH;
  for (int j = t; j < 512; j += 256) {
    const int node = node0 + j;
    if (node < NN) {
      rowBeg[node] = base + start[j];
      rowEnd[node] = base + start[j] + hist[j];
    }
  }
  __syncthreads();
  for (int j = t; j < 512; j += 256) hist[j] = start[j];  // reuse as cursors
  __syncthreads();
  for (int i = t; i < cnt; i += 256) {
    const unsigned long long pk = stg[base + i];
    const unsigned lo = (unsigned)pk;
    const int dl = (lo >> 17) & 511;
    const int pos = base + atomicAdd(&hist[dl], 1);
    __hip_bfloat16 hv = __float2bfloat16(__uint_as_float((unsigned)(pk >> 32)));
    edges[pos] = (lo & 0x1FFFFu) | ((unsigned)*(unsigned short*)&hv << 17);
  }
}

// ---------------- gather-aggregate + epilogue (R6/R8 proven geometry) ----------------
// 16-lane group per node; lane owns 8 cols; 8-deep batches; nt streaming.
__global__ __launch_bounds__(256) void kgather(const unsigned short* __restrict__ sup,
                                               const int* __restrict__ rowBeg,
                                               const int* __restrict__ rowEnd,
                                               const unsigned* __restrict__ edges,
                                               const float* __restrict__ feat,
                                               const float* __restrict__ bias,
                                               float* __restrict__ out) {
  const int n = blockIdx.x * 16 + (threadIdx.x >> 4);
  if (n >= NN) return;
  const int gl = threadIdx.x & 15;
  const int beg = rowBeg[n];
  const int end = rowEnd[n];
  float a0 = 0.f, a1 = 0.f, a2 = 0.f, a3 = 0.f, a4 = 0.f, a5 = 0.f, a6 = 0.f, a7 = 0.f;

  const char* supb = (const char*)sup;
  const unsigned glo = (unsigned)(gl << 4);

#define ACC8(q, rr)                                                        \
  {                                                                        \
    const float vv = __uint_as_float((rr >> 17) << 16);                    \
    a0 = fmaf(__uint_as_float(q.x << 16), vv, a0);                         \
    a1 = fmaf(__uint_as_float(q.x & 0xffff0000u), vv, a1);                 \
    a2 = fmaf(__uint_as_float(q.y << 16), vv, a2);                         \
    a3 = fmaf(__uint_as_float(q.y & 0xffff0000u), vv, a3);                 \
    a4 = fmaf(__uint_as_float(q.z << 16), vv, a4);                         \
    a5 = fmaf(__uint_as_float(q.z & 0xffff0000u), vv, a5);                 \
    a6 = fmaf(__uint_as_float(q.w << 16), vv, a6);                         \
    a7 = fmaf(__uint_as_float(q.w & 0xffff0000u), vv, a7);                 \
  }

  unsigned w = 0;
  if (beg + gl < end) w = __builtin_nontemporal_load(edges + beg + gl);

  for (int base = beg; base < end; base += 16) {
    int cnt = end - base;
    if (cnt > 16) cnt = 16;
    const unsigned wc = w;
    if (base + 16 + gl < end) w = __builtin_nontemporal_load(edges + base + 16 + gl);

    int i = 0;
    for (; i + 8 <= cnt; i += 8) {
      const unsigned r0 = __shfl(wc, i + 0, 16);
      const unsigned r1 = __shfl(wc, i + 1, 16);
      const unsigned r2 = __shfl(wc, i + 2, 16);
      const unsigned r3 = __shfl(wc, i + 3, 16);
      const unsigned r4 = __shfl(wc, i + 4, 16);
      const unsigned r5 = __shfl(wc, i + 5, 16);
      const unsigned r6 = __shfl(wc, i + 6, 16);
      const unsigned r7 = __shfl(wc, i + 7, 16);
      const uint4v q0 = *(const uint4v*)(supb + ((r0 & 0x1FFFFu) << 8) + glo);
      const uint4v q1 = *(const uint4v*)(supb + ((r1 & 0x1FFFFu) << 8) + glo);
      const uint4v q2 = *(const uint4v*)(supb + ((r2 & 0x1FFFFu) << 8) + glo);
      const uint4v q3 = *(const uint4v*)(supb + ((r3 & 0x1FFFFu) << 8) + glo);
      const uint4v q4 = *(const uint4v*)(supb + ((r4 & 0x1FFFFu) << 8) + glo);
      const uint4v q5 = *(const uint4v*)(supb + ((r5 & 0x1FFFFu) << 8) + glo);
      const uint4v q6 = *(const uint4v*)(supb + ((r6 & 0x1FFFFu) << 8) + glo);
      const uint4v q7 = *(const uint4v*)(supb + ((r7 & 0x1FFFFu) << 8) + glo);
      ACC8(q0, r0) ACC8(q1, r1) ACC8(q2, r2) ACC8(q3, r3)
      ACC8(q4, r4) ACC8(q5, r5) ACC8(q6, r6) ACC8(q7, r7)
    }
    for (; i < cnt; ++i) {
      const unsigned rr = __shfl(wc, i, 16);
      const uint4v q = *(const uint4v*)(supb + ((rr & 0x1FFFFu) << 8) + glo);
      ACC8(q, rr)
    }
  }
#undef ACC8

  const int c = gl << 3;
  const float4v b0 = *(const float4v*)(bias + c);
  const float4v b1 = *(const float4v*)(bias + c + 4);
  const float* frt = feat + (size_t)n * D + c;
  const float4v f0 = __builtin_nontemporal_load((const float4v*)frt);
  const float4v f1 = __builtin_nontemporal_load((const float4v*)(frt + 4));
  float4v o0, o1;
  o0.x = fmaxf(a0 + b0.x, 0.f) + f0.x;
  o0.y = fmaxf(a1 + b0.y, 0.f) + f0.y;
  o0.z = fmaxf(a2 + b0.z, 0.f) + f0.z;
  o0.w = fmaxf(a3 + b0.w, 0.f) + f0.w;
  o1.x = fmaxf(a4 + b1.x, 0.f) + f1.x;
  o1.y = fmaxf(a5 + b1.y, 0.f) + f1.y;
  o1.z = fmaxf(a6 + b1.z, 0.f) + f1.z;
  o1.w = fmaxf(a7 + b1.w, 0.f) + f1.w;
  float* orow = out + (size_t)n * D + c;
  __builtin_nontemporal_store(o0, (float4v*)orow);
  __builtin_nontemporal_store(o1, (float4v*)(orow + 4));
}

extern "C" void kernel_launch(void* const* d_in, const int* in_sizes, int n_in,
                              void* d_out, int out_size, void* d_ws, size_t ws_size,
                              hipStream_t stream) {
  const float* feat = (const float*)d_in[0];
  const int*   esrc = (const int*)d_in[1];
  const int*   edst = (const int*)d_in[2];
  const float* eval = (const float*)d_in[3];
  const float* W    = (const float*)d_in[4];
  const float* bias = (const float*)d_in[5];
  float* out = (float*)d_out;
  char*  ws  = (char*)d_ws;

  unsigned short*     sup    = (unsigned short*)(ws + SUP_OFF);
  int*                rowBeg = (int*)(ws + RB_OFF);
  int*                rowEnd = (int*)(ws + RE_OFF);
  int*                cursor = (int*)(ws + CUR_OFF);
  unsigned short*     Wt     = (unsigned short*)(ws + WT_OFF);
  unsigned long long* stg    = (unsigned long long*)(ws + STG_OFF);
  unsigned*           edges  = (unsigned*)(ws + EDG_OFF);

  // K0: W -> bf16^T + zero cursors
  k0_prep<<<64, 256, 0, stream>>>(W, Wt, cursor);
  // K1: MFMA GEMM
  kgemm<<<NGEMM, 256, 0, stream>>>(feat, Wt, sup);
  // K2: multisplit into padded buckets (no pre-hist / no scan)
  kpassA<<<NA, 256, 0, stream>>>(esrc, edst, eval, cursor, stg);
  // K3: per-bucket CSR finalize (padded layout, rowBeg/rowEnd)
  kpassB<<<NB, 256, 0, stream>>>(stg, cursor, rowBeg, rowEnd, edges);
  // K4: gather-aggregate + bias + relu + residual (R6 geometry)
  kgather<<<(NN + 15) / 16, 256, 0, stream>>>(sup, rowBeg, rowEnd, edges, feat, bias, out);
}

// Round 13
// 131.295 us; speedup vs baseline: 9.4301x; 1.0504x over previous
//
#include <hip/hip_runtime.h>
#include <hip/hip_bf16.h>

#define NN 100000
#define NE 1600000
#define D 128
#define NB 196   // buckets of 512 nodes (dst >> 9)
#define BSH 9
#define CAP 10240  // padded bucket capacity (mean 8192, sigma ~90 -> 22 sigma)

static constexpr int NA    = (NE + 4095) / 4096;   // 391 edge chunks
static constexpr int NGEMM = (NN + 63) / 64;       // 1563 gemm tiles

// ---------------- workspace layout ----------------
static constexpr size_t SUP_OFF    = 0;
static constexpr size_t SUP_BYTES  = (((size_t)NN * D * 2) + 15) & ~(size_t)15;   // 25.6 MB bf16
static constexpr size_t RB_OFF     = SUP_OFF + SUP_BYTES;
static constexpr size_t RB_BY      = (((size_t)NN * 4) + 15) & ~(size_t)15;
static constexpr size_t RE_OFF     = RB_OFF + RB_BY;
static constexpr size_t RE_BY      = (((size_t)NN * 4) + 15) & ~(size_t)15;
static constexpr size_t CUR_OFF    = RE_OFF + RE_BY;
static constexpr size_t CUR_BY     = (((size_t)NB * 4) + 15) & ~(size_t)15;
static constexpr size_t WT_OFF     = CUR_OFF + CUR_BY;
static constexpr size_t WT_BY      = (size_t)D * D * 2;                            // 32 KB bf16 W^T
static constexpr size_t STG_OFF    = WT_OFF + WT_BY;
static constexpr size_t STG_BY     = (size_t)NB * CAP * 8;                         // 16.1 MB
static constexpr size_t EDG_OFF    = STG_OFF + STG_BY;
static constexpr size_t EDG_BY     = (size_t)NB * CAP * 4;                         // 8.0 MB

typedef __attribute__((ext_vector_type(8))) short short8v;   // 8 bf16 (4 VGPRs)
typedef __attribute__((ext_vector_type(4))) float float4v;   // MFMA C/D + nt f32x4
typedef __attribute__((ext_vector_type(4))) unsigned uint4v; // nt u32x4

__device__ __forceinline__ unsigned pk_bf16(float a, float b) {
  __hip_bfloat16 x = __float2bfloat16(a), y = __float2bfloat16(b);
  return (unsigned)*(unsigned short*)&x | ((unsigned)*(unsigned short*)&y << 16);
}

// ---------------- K0: W -> bf16^T  +  zero bucket cursors ----------------
__global__ __launch_bounds__(256) void k0_prep(const float* __restrict__ W,
                                               unsigned short* __restrict__ Wt,
                                               int* __restrict__ cursor) {
  const int i = blockIdx.x * 256 + threadIdx.x;
  if (i < D * D) {
    const int k = i >> 7, c = i & 127;
    __hip_bfloat16 h = __float2bfloat16(W[i]);
    Wt[c * D + k] = *(unsigned short*)&h;
  }
  if (blockIdx.x == 0 && threadIdx.x < NB) cursor[threadIdx.x] = 0;
}

// ---------------- pass A: multisplit into PADDED buckets ----------------
// stg word: lo = src | (dst&511)<<17 ; hi = val fp32 bits; bucket b at stg + b*CAP
__global__ __launch_bounds__(256) void kpassA(const int* __restrict__ src,
                                              const int* __restrict__ dst,
                                              const float* __restrict__ val,
                                              int* __restrict__ cursor,
                                              unsigned long long* __restrict__ stg) {
  __shared__ int h4[4 * NB];
  __shared__ int h[NB];
  __shared__ int base[NB];
  const int t = threadIdx.x;
  for (int i = t; i < 4 * NB; i += 256) h4[i] = 0;
  __syncthreads();
  const int e0 = blockIdx.x * 4096;
  const int hb = (t >> 6) * NB;
  int d[16];
#pragma unroll
  for (int k = 0; k < 16; ++k) {
    const int e = e0 + t + k * 256;
    d[k] = (e < NE) ? dst[e] : -1;
    if (d[k] >= 0) atomicAdd(&h4[hb + (d[k] >> BSH)], 1);
  }
  __syncthreads();
  for (int i = t; i < NB; i += 256)
    h[i] = h4[i] + h4[NB + i] + h4[2 * NB + i] + h4[3 * NB + i];
  __syncthreads();
  for (int i = t; i < NB; i += 256)
    base[i] = h[i] ? atomicAdd(&cursor[i], h[i]) : 0;
  __syncthreads();
#pragma unroll
  for (int k = 0; k < 16; ++k) {
    const int e = e0 + t + k * 256;
    if (d[k] >= 0) {
      const int bk = d[k] >> BSH;
      const int pos = atomicAdd(&base[bk], 1);
      const unsigned lo = (unsigned)src[e] | ((unsigned)(d[k] & 511) << 17);
      const unsigned hi = __float_as_uint(val[e]);
      stg[(size_t)bk * CAP + pos] = (unsigned long long)lo | ((unsigned long long)hi << 32);
    }
  }
}

// ---------------- K2: passB (blocks 0..NB-1, FIRST) || MFMA GEMM (rest) ----------------
// passB and gemm are independent; passB-first ordering makes the 196 passB
// blocks run concurrently with gemm instead of serially after it.
__global__ __launch_bounds__(256) void k2_passB_gemm(const unsigned long long* __restrict__ stg,
                                                     const int* __restrict__ cursor,
                                                     int* __restrict__ rowBeg,
                                                     int* __restrict__ rowEnd,
                                                     unsigned* __restrict__ edges,
                                                     const float* __restrict__ feat,
                                                     const unsigned short* __restrict__ Wt,
                                                     unsigned short* __restrict__ sup) {
  const int t = threadIdx.x;
  if ((int)blockIdx.x < NB) {
    // ---- passB: per-bucket exact CSR in padded layout; 4B edge records ----
    __shared__ int hist[512];
    __shared__ int start[512];
    __shared__ int psum[256];
    const int b = blockIdx.x;
    const int cnt = cursor[b];
    const int base = b * CAP;
    hist[t] = 0;
    hist[t + 256] = 0;
    __syncthreads();
    for (int i = t; i < cnt; i += 256)
      atomicAdd(&hist[((unsigned)stg[base + i] >> 17) & 511], 1);
    __syncthreads();
    const int h0 = hist[2 * t], h1 = hist[2 * t + 1];
    const int p = h0 + h1;
    psum[t] = p;
    __syncthreads();
#pragma unroll
    for (int off = 1; off < 256; off <<= 1) {
      const int x = (t >= off) ? psum[t - off] : 0;
      __syncthreads();
      psum[t] += x;
      __syncthreads();
    }
    const int ex = psum[t] - p;
    start[2 * t] = ex;
    start[2 * t + 1] = ex + h0;
    __syncthreads();
    const int node0 = b << BSH;
    for (int j = t; j < 512; j += 256) {
      const int node = node0 + j;
      if (node < NN) {
        rowBeg[node] = base + start[j];
        rowEnd[node] = base + start[j] + hist[j];
      }
    }
    __syncthreads();
    for (int j = t; j < 512; j += 256) hist[j] = start[j];  // reuse as cursors
    __syncthreads();
    for (int i = t; i < cnt; i += 256) {
      const unsigned long long pk = stg[base + i];
      const unsigned lo = (unsigned)pk;
      const int dl = (lo >> 17) & 511;
      const int pos = base + atomicAdd(&hist[dl], 1);
      __hip_bfloat16 hv = __float2bfloat16(__uint_as_float((unsigned)(pk >> 32)));
      edges[pos] = (lo & 0x1FFFFu) | ((unsigned)*(unsigned short*)&hv << 17);
    }
  } else {
    // ---- GEMM tile: 64 rows x 128 cols, 4 waves x 16 rows ----
    const int gid = (int)blockIdx.x - NB;
    __shared__ char Wl[32768];
    {
      const uint4* g = (const uint4*)Wt;
      for (int i = t; i < 2048; i += 256) {
        const int b = i << 4;
        *(uint4*)&Wl[b ^ (((b >> 8) & 7) << 4)] = g[i];
      }
    }
    __syncthreads();

    const int wv = t >> 6, l = t & 63;
    const int lm = l & 15, lk = l >> 4;
    const int r0 = gid * 64 + wv * 16;
    int row = r0 + lm;
    if (row >= NN) row = NN - 1;  // clamp; stores are guarded
    const float* fr = feat + (size_t)row * D;

    short8v A[4];
#pragma unroll
    for (int ks = 0; ks < 4; ++ks) {
      const float4 u = *(const float4*)(fr + ks * 32 + lk * 8);
      const float4 v = *(const float4*)(fr + ks * 32 + lk * 8 + 4);
      union { unsigned w[4]; short8v s; } cv;
      cv.w[0] = pk_bf16(u.x, u.y);
      cv.w[1] = pk_bf16(u.z, u.w);
      cv.w[2] = pk_bf16(v.x, v.y);
      cv.w[3] = pk_bf16(v.z, v.w);
      A[ks] = cv.s;
    }

    float4v acc[8];
#pragma unroll
    for (int ct = 0; ct < 8; ++ct) acc[ct] = (float4v){0.f, 0.f, 0.f, 0.f};

#pragma unroll
    for (int ct = 0; ct < 8; ++ct) {
      const int c = ct * 16 + lm;
#pragma unroll
      for (int ks = 0; ks < 4; ++ks) {
        int b = c * 256 + ks * 64 + lk * 16;
        b ^= ((c & 7) << 4);
        const short8v Bf = *(const short8v*)&Wl[b];
        acc[ct] = __builtin_amdgcn_mfma_f32_16x16x32_bf16(A[ks], Bf, acc[ct], 0, 0, 0);
      }
    }

#pragma unroll
    for (int j = 0; j < 4; ++j) {
      const int rr = r0 + lk * 4 + j;
      if (rr < NN) {
        unsigned short* srow = sup + (size_t)rr * D + lm;
#pragma unroll
        for (int ct = 0; ct < 8; ++ct) {
          __hip_bfloat16 h = __float2bfloat16(acc[ct][j]);
          srow[ct * 16] = *(unsigned short*)&h;
        }
      }
    }
  }
}

// ---------------- gather-aggregate + epilogue (R6/R8 proven geometry) ----------------
// 16-lane group per node; lane owns 8 cols; 8-deep batches; nt streaming.
__global__ __launch_bounds__(256) void kgather(const unsigned short* __restrict__ sup,
                                               const int* __restrict__ rowBeg,
                                               const int* __restrict__ rowEnd,
                                               const unsigned* __restrict__ edges,
                                               const float* __restrict__ feat,
                                               const float* __restrict__ bias,
                                               float* __restrict__ out) {
  const int n = blockIdx.x * 16 + (threadIdx.x >> 4);
  if (n >= NN) return;
  const int gl = threadIdx.x & 15;
  const int beg = rowBeg[n];
  const int end = rowEnd[n];
  float a0 = 0.f, a1 = 0.f, a2 = 0.f, a3 = 0.f, a4 = 0.f, a5 = 0.f, a6 = 0.f, a7 = 0.f;

  const char* supb = (const char*)sup;
  const unsigned glo = (unsigned)(gl << 4);

#define ACC8(q, rr)                                                        \
  {                                                                        \
    const float vv = __uint_as_float((rr >> 17) << 16);                    \
    a0 = fmaf(__uint_as_float(q.x << 16), vv, a0);                         \
    a1 = fmaf(__uint_as_float(q.x & 0xffff0000u), vv, a1);                 \
    a2 = fmaf(__uint_as_float(q.y << 16), vv, a2);                         \
    a3 = fmaf(__uint_as_float(q.y & 0xffff0000u), vv, a3);                 \
    a4 = fmaf(__uint_as_float(q.z << 16), vv, a4);                         \
    a5 = fmaf(__uint_as_float(q.z & 0xffff0000u), vv, a5);                 \
    a6 = fmaf(__uint_as_float(q.w << 16), vv, a6);                         \
    a7 = fmaf(__uint_as_float(q.w & 0xffff0000u), vv, a7);                 \
  }

  unsigned w = 0;
  if (beg + gl < end) w = __builtin_nontemporal_load(edges + beg + gl);

  for (int base = beg; base < end; base += 16) {
    int cnt = end - base;
    if (cnt > 16) cnt = 16;
    const unsigned wc = w;
    if (base + 16 + gl < end) w = __builtin_nontemporal_load(edges + base + 16 + gl);

    int i = 0;
    for (; i + 8 <= cnt; i += 8) {
      const unsigned r0 = __shfl(wc, i + 0, 16);
      const unsigned r1 = __shfl(wc, i + 1, 16);
      const unsigned r2 = __shfl(wc, i + 2, 16);
      const unsigned r3 = __shfl(wc, i + 3, 16);
      const unsigned r4 = __shfl(wc, i + 4, 16);
      const unsigned r5 = __shfl(wc, i + 5, 16);
      const unsigned r6 = __shfl(wc, i + 6, 16);
      const unsigned r7 = __shfl(wc, i + 7, 16);
      const uint4v q0 = *(const uint4v*)(supb + ((r0 & 0x1FFFFu) << 8) + glo);
      const uint4v q1 = *(const uint4v*)(supb + ((r1 & 0x1FFFFu) << 8) + glo);
      const uint4v q2 = *(const uint4v*)(supb + ((r2 & 0x1FFFFu) << 8) + glo);
      const uint4v q3 = *(const uint4v*)(supb + ((r3 & 0x1FFFFu) << 8) + glo);
      const uint4v q4 = *(const uint4v*)(supb + ((r4 & 0x1FFFFu) << 8) + glo);
      const uint4v q5 = *(const uint4v*)(supb + ((r5 & 0x1FFFFu) << 8) + glo);
      const uint4v q6 = *(const uint4v*)(supb + ((r6 & 0x1FFFFu) << 8) + glo);
      const uint4v q7 = *(const uint4v*)(supb + ((r7 & 0x1FFFFu) << 8) + glo);
      ACC8(q0, r0) ACC8(q1, r1) ACC8(q2, r2) ACC8(q3, r3)
      ACC8(q4, r4) ACC8(q5, r5) ACC8(q6, r6) ACC8(q7, r7)
    }
    for (; i < cnt; ++i) {
      const unsigned rr = __shfl(wc, i, 16);
      const uint4v q = *(const uint4v*)(supb + ((rr & 0x1FFFFu) << 8) + glo);
      ACC8(q, rr)
    }
  }
#undef ACC8

  const int c = gl << 3;
  const float4v b0 = *(const float4v*)(bias + c);
  const float4v b1 = *(const float4v*)(bias + c + 4);
  const float* frt = feat + (size_t)n * D + c;
  const float4v f0 = __builtin_nontemporal_load((const float4v*)frt);
  const float4v f1 = __builtin_nontemporal_load((const float4v*)(frt + 4));
  float4v o0, o1;
  o0.x = fmaxf(a0 + b0.x, 0.f) + f0.x;
  o0.y = fmaxf(a1 + b0.y, 0.f) + f0.y;
  o0.z = fmaxf(a2 + b0.z, 0.f) + f0.z;
  o0.w = fmaxf(a3 + b0.w, 0.f) + f0.w;
  o1.x = fmaxf(a4 + b1.x, 0.f) + f1.x;
  o1.y = fmaxf(a5 + b1.y, 0.f) + f1.y;
  o1.z = fmaxf(a6 + b1.z, 0.f) + f1.z;
  o1.w = fmaxf(a7 + b1.w, 0.f) + f1.w;
  float* orow = out + (size_t)n * D + c;
  __builtin_nontemporal_store(o0, (float4v*)orow);
  __builtin_nontemporal_store(o1, (float4v*)(orow + 4));
}

extern "C" void kernel_launch(void* const* d_in, const int* in_sizes, int n_in,
                              void* d_out, int out_size, void* d_ws, size_t ws_size,
                              hipStream_t stream) {
  const float* feat = (const float*)d_in[0];
  const int*   esrc = (const int*)d_in[1];
  const int*   edst = (const int*)d_in[2];
  const float* eval = (const float*)d_in[3];
  const float* W    = (const float*)d_in[4];
  const float* bias = (const float*)d_in[5];
  float* out = (float*)d_out;
  char*  ws  = (char*)d_ws;

  unsigned short*     sup    = (unsigned short*)(ws + SUP_OFF);
  int*                rowBeg = (int*)(ws + RB_OFF);
  int*                rowEnd = (int*)(ws + RE_OFF);
  int*                cursor = (int*)(ws + CUR_OFF);
  unsigned short*     Wt     = (unsigned short*)(ws + WT_OFF);
  unsigned long long* stg    = (unsigned long long*)(ws + STG_OFF);
  unsigned*           edges  = (unsigned*)(ws + EDG_OFF);

  // K0: W -> bf16^T + zero cursors
  k0_prep<<<64, 256, 0, stream>>>(W, Wt, cursor);
  // K1: multisplit into padded buckets
  kpassA<<<NA, 256, 0, stream>>>(esrc, edst, eval, cursor, stg);
  // K2: passB (blocks 0..195, first) || MFMA GEMM (blocks 196..)
  k2_passB_gemm<<<NB + NGEMM, 256, 0, stream>>>(stg, cursor, rowBeg, rowEnd, edges,
                                                feat, Wt, sup);
  // K3: gather-aggregate + bias + relu + residual
  kgather<<<(NN + 15) / 16, 256, 0, stream>>>(sup, rowBeg, rowEnd, edges, feat, bias, out);
}

// Round 14
// 128.001 us; speedup vs baseline: 9.6728x; 1.0257x over previous
//
#include <hip/hip_runtime.h>
#include <hip/hip_bf16.h>

#define NN 100000
#define NE 1600000
#define D 128
#define NB 196   // buckets of 512 nodes (dst >> 9)
#define BSH 9
#define CAP 10240  // padded bucket capacity (mean 8192, sigma ~90 -> 22 sigma)

static constexpr int NA    = (NE + 4095) / 4096;   // 391 edge chunks
static constexpr int NGEMM = (NN + 63) / 64;       // 1563 gemm tiles
static constexpr int GH1   = 781;                  // gemm tiles fused into K1
static constexpr int GH2   = NGEMM - GH1;          // 782 gemm tiles fused into K2

// ---------------- workspace layout ----------------
static constexpr size_t SUP_OFF    = 0;
static constexpr size_t SUP_BYTES  = (((size_t)NN * D * 2) + 15) & ~(size_t)15;   // 25.6 MB bf16
static constexpr size_t RB_OFF     = SUP_OFF + SUP_BYTES;
static constexpr size_t RB_BY      = (((size_t)NN * 4) + 15) & ~(size_t)15;
static constexpr size_t RE_OFF     = RB_OFF + RB_BY;
static constexpr size_t RE_BY      = (((size_t)NN * 4) + 15) & ~(size_t)15;
static constexpr size_t CUR_OFF    = RE_OFF + RE_BY;
static constexpr size_t CUR_BY     = (((size_t)NB * 4) + 15) & ~(size_t)15;
static constexpr size_t WT_OFF     = CUR_OFF + CUR_BY;
static constexpr size_t WT_BY      = (size_t)D * D * 2;                            // 32 KB bf16 W^T
static constexpr size_t STG_OFF    = WT_OFF + WT_BY;
static constexpr size_t STG_BY     = (size_t)NB * CAP * 8;                         // 16.1 MB
static constexpr size_t EDG_OFF    = STG_OFF + STG_BY;
static constexpr size_t EDG_BY     = (size_t)NB * CAP * 4;                         // 8.0 MB

typedef __attribute__((ext_vector_type(8))) short short8v;   // 8 bf16 (4 VGPRs)
typedef __attribute__((ext_vector_type(4))) float float4v;   // MFMA C/D + nt f32x4
typedef __attribute__((ext_vector_type(4))) unsigned uint4v; // nt u32x4

__device__ __forceinline__ unsigned pk_bf16(float a, float b) {
  __hip_bfloat16 x = __float2bfloat16(a), y = __float2bfloat16(b);
  return (unsigned)*(unsigned short*)&x | ((unsigned)*(unsigned short*)&y << 16);
}

// ---------------- K0: W -> bf16^T  +  zero bucket cursors ----------------
__global__ __launch_bounds__(256) void k0_prep(const float* __restrict__ W,
                                               unsigned short* __restrict__ Wt,
                                               int* __restrict__ cursor) {
  const int i = blockIdx.x * 256 + threadIdx.x;
  if (i < D * D) {
    const int k = i >> 7, c = i & 127;
    __hip_bfloat16 h = __float2bfloat16(W[i]);
    Wt[c * D + k] = *(unsigned short*)&h;
  }
  if (blockIdx.x == 0 && threadIdx.x < NB) cursor[threadIdx.x] = 0;
}

// ---------------- shared gemm tile body (64 rows x 128 cols, 4 waves) ----------------
__device__ __forceinline__ void gemm_tile(const int gid, const int t,
                                          const float* __restrict__ feat,
                                          const unsigned short* __restrict__ Wt,
                                          unsigned short* __restrict__ sup,
                                          char* Wl) {
  {
    const uint4* g = (const uint4*)Wt;
    for (int i = t; i < 2048; i += 256) {
      const int b = i << 4;
      *(uint4*)&Wl[b ^ (((b >> 8) & 7) << 4)] = g[i];
    }
  }
  __syncthreads();

  const int wv = t >> 6, l = t & 63;
  const int lm = l & 15, lk = l >> 4;
  const int r0 = gid * 64 + wv * 16;
  int row = r0 + lm;
  if (row >= NN) row = NN - 1;  // clamp; stores are guarded
  const float* fr = feat + (size_t)row * D;

  short8v A[4];
#pragma unroll
  for (int ks = 0; ks < 4; ++ks) {
    const float4 u = *(const float4*)(fr + ks * 32 + lk * 8);
    const float4 v = *(const float4*)(fr + ks * 32 + lk * 8 + 4);
    union { unsigned w[4]; short8v s; } cv;
    cv.w[0] = pk_bf16(u.x, u.y);
    cv.w[1] = pk_bf16(u.z, u.w);
    cv.w[2] = pk_bf16(v.x, v.y);
    cv.w[3] = pk_bf16(v.z, v.w);
    A[ks] = cv.s;
  }

  float4v acc[8];
#pragma unroll
  for (int ct = 0; ct < 8; ++ct) acc[ct] = (float4v){0.f, 0.f, 0.f, 0.f};

#pragma unroll
  for (int ct = 0; ct < 8; ++ct) {
    const int c = ct * 16 + lm;
#pragma unroll
    for (int ks = 0; ks < 4; ++ks) {
      int b = c * 256 + ks * 64 + lk * 16;
      b ^= ((c & 7) << 4);
      const short8v Bf = *(const short8v*)&Wl[b];
      acc[ct] = __builtin_amdgcn_mfma_f32_16x16x32_bf16(A[ks], Bf, acc[ct], 0, 0, 0);
    }
  }

#pragma unroll
  for (int j = 0; j < 4; ++j) {
    const int rr = r0 + lk * 4 + j;
    if (rr < NN) {
      unsigned short* srow = sup + (size_t)rr * D + lm;
#pragma unroll
      for (int ct = 0; ct < 8; ++ct) {
        __hip_bfloat16 h = __float2bfloat16(acc[ct][j]);
        srow[ct * 16] = *(unsigned short*)&h;
      }
    }
  }
}

// ---------------- K1: passA (blocks 0..NA-1, FIRST) || gemm chunk 1 ----------------
// One 32KB LDS buffer aliased by both branches (avoid branch-LDS summing).
__global__ __launch_bounds__(256) void k1_passA_gemm(const int* __restrict__ src,
                                                     const int* __restrict__ dst,
                                                     const float* __restrict__ val,
                                                     int* __restrict__ cursor,
                                                     unsigned long long* __restrict__ stg,
                                                     const float* __restrict__ feat,
                                                     const unsigned short* __restrict__ Wt,
                                                     unsigned short* __restrict__ sup) {
  __shared__ char ldsbuf[32768];
  const int t = threadIdx.x;
  if ((int)blockIdx.x < NA) {
    // ---- pass A: multisplit into padded buckets (single LDS histogram) ----
    int* h    = (int*)ldsbuf;        // [NB]
    int* base = ((int*)ldsbuf) + NB; // [NB]
    for (int i = t; i < NB; i += 256) h[i] = 0;
    __syncthreads();
    const int e0 = blockIdx.x * 4096;
    int d[16];
#pragma unroll
    for (int k = 0; k < 16; ++k) {
      const int e = e0 + t + k * 256;
      d[k] = (e < NE) ? dst[e] : -1;
      if (d[k] >= 0) atomicAdd(&h[d[k] >> BSH], 1);
    }
    __syncthreads();
    for (int i = t; i < NB; i += 256)
      base[i] = h[i] ? atomicAdd(&cursor[i], h[i]) : 0;
    __syncthreads();
#pragma unroll
    for (int k = 0; k < 16; ++k) {
      const int e = e0 + t + k * 256;
      if (d[k] >= 0) {
        const int bk = d[k] >> BSH;
        const int pos = atomicAdd(&base[bk], 1);
        const unsigned lo = (unsigned)src[e] | ((unsigned)(d[k] & 511) << 17);
        const unsigned hi = __float_as_uint(val[e]);
        stg[(size_t)bk * CAP + pos] = (unsigned long long)lo | ((unsigned long long)hi << 32);
      }
    }
  } else {
    gemm_tile((int)blockIdx.x - NA, t, feat, Wt, sup, ldsbuf);
  }
}

// ---------------- K2: passB (blocks 0..NB-1, FIRST) || gemm chunk 2 ----------------
__global__ __launch_bounds__(256) void k2_passB_gemm(const unsigned long long* __restrict__ stg,
                                                     const int* __restrict__ cursor,
                                                     int* __restrict__ rowBeg,
                                                     int* __restrict__ rowEnd,
                                                     unsigned* __restrict__ edges,
                                                     const float* __restrict__ feat,
                                                     const unsigned short* __restrict__ Wt,
                                                     unsigned short* __restrict__ sup) {
  __shared__ char ldsbuf[32768];
  const int t = threadIdx.x;
  if ((int)blockIdx.x < NB) {
    // ---- passB: per-bucket exact CSR in padded layout; 4B edge records ----
    int* hist  = (int*)ldsbuf;          // [512]
    int* start = ((int*)ldsbuf) + 512;  // [512]
    int* psum  = ((int*)ldsbuf) + 1024; // [256]
    const int b = blockIdx.x;
    const int cnt = cursor[b];
    const int base = b * CAP;
    hist[t] = 0;
    hist[t + 256] = 0;
    __syncthreads();
    for (int i = t; i < cnt; i += 256)
      atomicAdd(&hist[((unsigned)stg[base + i] >> 17) & 511], 1);
    __syncthreads();
    const int h0 = hist[2 * t], h1 = hist[2 * t + 1];
    const int p = h0 + h1;
    psum[t] = p;
    __syncthreads();
#pragma unroll
    for (int off = 1; off < 256; off <<= 1) {
      const int x = (t >= off) ? psum[t - off] : 0;
      __syncthreads();
      psum[t] += x;
      __syncthreads();
    }
    const int ex = psum[t] - p;
    start[2 * t] = ex;
    start[2 * t + 1] = ex + h0;
    __syncthreads();
    const int node0 = b << BSH;
    for (int j = t; j < 512; j += 256) {
      const int node = node0 + j;
      if (node < NN) {
        rowBeg[node] = base + start[j];
        rowEnd[node] = base + start[j] + hist[j];
      }
    }
    __syncthreads();
    for (int j = t; j < 512; j += 256) hist[j] = start[j];  // reuse as cursors
    __syncthreads();
    for (int i = t; i < cnt; i += 256) {
      const unsigned long long pk = stg[base + i];
      const unsigned lo = (unsigned)pk;
      const int dl = (lo >> 17) & 511;
      const int pos = base + atomicAdd(&hist[dl], 1);
      __hip_bfloat16 hv = __float2bfloat16(__uint_as_float((unsigned)(pk >> 32)));
      edges[pos] = (lo & 0x1FFFFu) | ((unsigned)*(unsigned short*)&hv << 17);
    }
  } else {
    gemm_tile((int)blockIdx.x - NB + GH1, t, feat, Wt, sup, ldsbuf);
  }
}

// ---------------- gather-aggregate + epilogue (proven geometry, unchanged) ----------------
__global__ __launch_bounds__(256) void kgather(const unsigned short* __restrict__ sup,
                                               const int* __restrict__ rowBeg,
                                               const int* __restrict__ rowEnd,
                                               const unsigned* __restrict__ edges,
                                               const float* __restrict__ feat,
                                               const float* __restrict__ bias,
                                               float* __restrict__ out) {
  const int n = blockIdx.x * 16 + (threadIdx.x >> 4);
  if (n >= NN) return;
  const int gl = threadIdx.x & 15;
  const int beg = rowBeg[n];
  const int end = rowEnd[n];
  float a0 = 0.f, a1 = 0.f, a2 = 0.f, a3 = 0.f, a4 = 0.f, a5 = 0.f, a6 = 0.f, a7 = 0.f;

  const char* supb = (const char*)sup;
  const unsigned glo = (unsigned)(gl << 4);

#define ACC8(q, rr)                                                        \
  {                                                                        \
    const float vv = __uint_as_float((rr >> 17) << 16);                    \
    a0 = fmaf(__uint_as_float(q.x << 16), vv, a0);                         \
    a1 = fmaf(__uint_as_float(q.x & 0xffff0000u), vv, a1);                 \
    a2 = fmaf(__uint_as_float(q.y << 16), vv, a2);                         \
    a3 = fmaf(__uint_as_float(q.y & 0xffff0000u), vv, a3);                 \
    a4 = fmaf(__uint_as_float(q.z << 16), vv, a4);                         \
    a5 = fmaf(__uint_as_float(q.z & 0xffff0000u), vv, a5);                 \
    a6 = fmaf(__uint_as_float(q.w << 16), vv, a6);                         \
    a7 = fmaf(__uint_as_float(q.w & 0xffff0000u), vv, a7);                 \
  }

  unsigned w = 0;
  if (beg + gl < end) w = __builtin_nontemporal_load(edges + beg + gl);

  for (int base = beg; base < end; base += 16) {
    int cnt = end - base;
    if (cnt > 16) cnt = 16;
    const unsigned wc = w;
    if (base + 16 + gl < end) w = __builtin_nontemporal_load(edges + base + 16 + gl);

    int i = 0;
    for (; i + 8 <= cnt; i += 8) {
      const unsigned r0 = __shfl(wc, i + 0, 16);
      const unsigned r1 = __shfl(wc, i + 1, 16);
      const unsigned r2 = __shfl(wc, i + 2, 16);
      const unsigned r3 = __shfl(wc, i + 3, 16);
      const unsigned r4 = __shfl(wc, i + 4, 16);
      const unsigned r5 = __shfl(wc, i + 5, 16);
      const unsigned r6 = __shfl(wc, i + 6, 16);
      const unsigned r7 = __shfl(wc, i + 7, 16);
      const uint4v q0 = *(const uint4v*)(supb + ((r0 & 0x1FFFFu) << 8) + glo);
      const uint4v q1 = *(const uint4v*)(supb + ((r1 & 0x1FFFFu) << 8) + glo);
      const uint4v q2 = *(const uint4v*)(supb + ((r2 & 0x1FFFFu) << 8) + glo);
      const uint4v q3 = *(const uint4v*)(supb + ((r3 & 0x1FFFFu) << 8) + glo);
      const uint4v q4 = *(const uint4v*)(supb + ((r4 & 0x1FFFFu) << 8) + glo);
      const uint4v q5 = *(const uint4v*)(supb + ((r5 & 0x1FFFFu) << 8) + glo);
      const uint4v q6 = *(const uint4v*)(supb + ((r6 & 0x1FFFFu) << 8) + glo);
      const uint4v q7 = *(const uint4v*)(supb + ((r7 & 0x1FFFFu) << 8) + glo);
      ACC8(q0, r0) ACC8(q1, r1) ACC8(q2, r2) ACC8(q3, r3)
      ACC8(q4, r4) ACC8(q5, r5) ACC8(q6, r6) ACC8(q7, r7)
    }
    for (; i < cnt; ++i) {
      const unsigned rr = __shfl(wc, i, 16);
      const uint4v q = *(const uint4v*)(supb + ((rr & 0x1FFFFu) << 8) + glo);
      ACC8(q, rr)
    }
  }
#undef ACC8

  const int c = gl << 3;
  const float4v b0 = *(const float4v*)(bias + c);
  const float4v b1 = *(const float4v*)(bias + c + 4);
  const float* frt = feat + (size_t)n * D + c;
  const float4v f0 = __builtin_nontemporal_load((const float4v*)frt);
  const float4v f1 = __builtin_nontemporal_load((const float4v*)(frt + 4));
  float4v o0, o1;
  o0.x = fmaxf(a0 + b0.x, 0.f) + f0.x;
  o0.y = fmaxf(a1 + b0.y, 0.f) + f0.y;
  o0.z = fmaxf(a2 + b0.z, 0.f) + f0.z;
  o0.w = fmaxf(a3 + b0.w, 0.f) + f0.w;
  o1.x = fmaxf(a4 + b1.x, 0.f) + f1.x;
  o1.y = fmaxf(a5 + b1.y, 0.f) + f1.y;
  o1.z = fmaxf(a6 + b1.z, 0.f) + f1.z;
  o1.w = fmaxf(a7 + b1.w, 0.f) + f1.w;
  float* orow = out + (size_t)n * D + c;
  __builtin_nontemporal_store(o0, (float4v*)orow);
  __builtin_nontemporal_store(o1, (float4v*)(orow + 4));
}

extern "C" void kernel_launch(void* const* d_in, const int* in_sizes, int n_in,
                              void* d_out, int out_size, void* d_ws, size_t ws_size,
                              hipStream_t stream) {
  const float* feat = (const float*)d_in[0];
  const int*   esrc = (const int*)d_in[1];
  const int*   edst = (const int*)d_in[2];
  const float* eval = (const float*)d_in[3];
  const float* W    = (const float*)d_in[4];
  const float* bias = (const float*)d_in[5];
  float* out = (float*)d_out;
  char*  ws  = (char*)d_ws;

  unsigned short*     sup    = (unsigned short*)(ws + SUP_OFF);
  int*                rowBeg = (int*)(ws + RB_OFF);
  int*                rowEnd = (int*)(ws + RE_OFF);
  int*                cursor = (int*)(ws + CUR_OFF);
  unsigned short*     Wt     = (unsigned short*)(ws + WT_OFF);
  unsigned long long* stg    = (unsigned long long*)(ws + STG_OFF);
  unsigned*           edges  = (unsigned*)(ws + EDG_OFF);

  // K0: W -> bf16^T + zero cursors
  k0_prep<<<64, 256, 0, stream>>>(W, Wt, cursor);
  // K1: passA (blocks 0..390, first) || gemm chunk 1 (781 tiles)
  k1_passA_gemm<<<NA + GH1, 256, 0, stream>>>(esrc, edst, eval, cursor, stg, feat, Wt, sup);
  // K2: passB (blocks 0..195, first) || gemm chunk 2 (782 tiles)
  k2_passB_gemm<<<NB + GH2, 256, 0, stream>>>(stg, cursor, rowBeg, rowEnd, edges,
                                              feat, Wt, sup);
  // K3: gather-aggregate + bias + relu + residual
  kgather<<<(NN + 15) / 16, 256, 0, stream>>>(sup, rowBeg, rowEnd, edges, feat, bias, out);
}